// Round 5
// 511.714 us; speedup vs baseline: 3.0812x; 3.0812x over previous
//
#include <hip/hip_runtime.h>
#include <math.h>

#define BSZ 16
#define NH  8
#define SEQ 1024
#define DK  128
#define QB  64      // q-rows per block (4 waves x 16)
#define KB  64      // k-rows per LDS tile
#define NT  256
#define TOPK 5
#define NC   8      // tracked candidates (top-8)
#define EPS_REF 4e-3f

typedef _Float16 half8 __attribute__((ext_vector_type(8)));
typedef float f32x4 __attribute__((ext_vector_type(4)));

#define INV2P11 4.8828125e-4f          // 2^-11

// insert (x,xi) into sorted-descending top-NC (value,index) pairs
__device__ __forceinline__ void ins8p(float (&t)[NC], int (&ti)[NC], float x, int xi) {
    #pragma unroll
    for (int i = 0; i < NC; ++i) {
        bool gt = x > t[i];
        float tv = t[i]; int tiv = ti[i];
        t[i]  = gt ? x  : tv;
        ti[i] = gt ? xi : tiv;
        x  = gt ? tv  : x;
        xi = gt ? tiv : xi;
    }
}

// EXACT replica of the round-0 (reference-matching) fp32 scorer:
// single-accumulator sequential fmaf chain over d, then * scale.
__device__ __forceinline__ float ref_score(const float* __restrict__ qp,
                                           const float* __restrict__ kp,
                                           float scale) {
    const float4* q4 = (const float4*)qp;
    const float4* k4 = (const float4*)kp;
    float a0 = 0.f;
    #pragma unroll 8
    for (int c = 0; c < DK / 4; ++c) {
        float4 kx = k4[c];
        float4 t0 = q4[c];
        a0 = fmaf(kx.x, t0.x, a0);
        a0 = fmaf(kx.y, t0.y, a0);
        a0 = fmaf(kx.z, t0.z, a0);
        a0 = fmaf(kx.w, t0.w, a0);
    }
    return a0 * scale;
}

__launch_bounds__(NT, 4)
__global__ void attn_topk_mfma(const float* __restrict__ Q,
                               const float* __restrict__ Km,
                               const float* __restrict__ V,
                               const int* __restrict__ kidx_ptr,
                               float* __restrict__ out)
{
    const int bh   = blockIdx.y;
    const int qb   = ((int)gridDim.x - 1 - (int)blockIdx.x) * QB;  // heavy blocks first
    const int tid  = threadIdx.x;
    const int lane = tid & 63;
    const int w    = tid >> 6;          // wave 0..3
    const int c    = lane & 15;         // q-column within wave tile
    const int grp  = lane >> 4;         // 0..3
    const int Kv   = *kidx_ptr;         // 5

    // K tile staged as split-f16 (hi + mid*2^-11), XOR-swizzled rows
    __shared__ __align__(16) _Float16 khi [KB * DK];
    __shared__ __align__(16) _Float16 kmid[KB * DK];
    __shared__ float s_coef[4][16][NC];
    __shared__ int   s_idx [4][16][NC];
    __shared__ float s_ext [4][16];
    __shared__ int   s_cnt [4][16];
    __shared__ float s_sv  [DK];
    __shared__ float s_svp [2][DK];

    // ---- per-bh V column sum (only needed for rows 1..Kv-1, which live in qb==0) ----
    if (qb == 0) {
        const float* vb = V + (size_t)bh * SEQ * DK;
        const int col = tid & 127, hf = tid >> 7;
        float a = 0.f;
        #pragma unroll 8
        for (int j = hf * 512; j < hf * 512 + 512; ++j)
            a += vb[(size_t)j * DK + col];
        s_svp[hf][col] = a;
        __syncthreads();
        if (tid < DK) s_sv[tid] = s_svp[0][tid] + s_svp[1][tid];
        // s_sv read only after later barriers
    }

    // ---- load this wave's Q fragments (16 rows), split hi/mid, scale post-dot ----
    const int qrow = qb + w * 16 + c;
    const float scale = 0.08838834764831845f;          // 1/sqrt(128)
    half8 qhi[4], qmid[4];
    {
        const float* qp = Q + ((size_t)bh * SEQ + qrow) * DK;
        #pragma unroll
        for (int d = 0; d < 4; ++d) {
            const float4* p4 = (const float4*)(qp + d * 32 + grp * 8);
            float4 f0 = p4[0], f1 = p4[1];
            float v[8] = {f0.x, f0.y, f0.z, f0.w, f1.x, f1.y, f1.z, f1.w};
            #pragma unroll
            for (int j = 0; j < 8; ++j) {
                _Float16 h = (_Float16)v[j];
                float r = v[j] - (float)h;
                qhi[d][j]  = h;
                qmid[d][j] = (_Float16)(r * 2048.0f);
            }
        }
    }

    // ---- streaming state: top-8 (val,idx) + online sum of exp(s - max) ----
    float t[NC]; int ti[NC];
    #pragma unroll
    for (int i = 0; i < NC; ++i) { t[i] = -INFINITY; ti[i] = 0; }
    float Zr = 0.f;

    const int qmax_w = qb + w * 16 + 15;
    const int ntile  = qb / KB + 1;
    const float* kb_g = Km + (size_t)bh * SEQ * DK;

    for (int kt = 0; kt < ntile; ++kt) {
        __syncthreads();                 // previous tile's reads complete
        // ---- stage K tile kt: split hi/mid, swizzled ----
        {
            const float* src = kb_g + (size_t)kt * KB * DK;
            #pragma unroll
            for (int it = 0; it < 4; ++it) {
                int e   = it * 2048 + tid * 8;    // element in 64x128 tile
                int row = e >> 7;
                int d0  = e & 127;
                const float4* g4 = (const float4*)(src + (size_t)row * DK + d0);
                float4 f0 = g4[0], f1 = g4[1];
                float v[8] = {f0.x, f0.y, f0.z, f0.w, f1.x, f1.y, f1.z, f1.w};
                half8 hv, mv;
                #pragma unroll
                for (int j = 0; j < 8; ++j) {
                    _Float16 h = (_Float16)v[j];
                    float r = v[j] - (float)h;
                    hv[j] = h;
                    mv[j] = (_Float16)(r * 2048.0f);
                }
                int off = row * 256 + ((d0 * 2) ^ ((row & 7) << 4));
                *(half8*)((char*)khi  + off) = hv;
                *(half8*)((char*)kmid + off) = mv;
            }
        }
        __syncthreads();

        // ---- compute: S^T frags = mfma(K_frag, Q_frag); stream scores ----
        const int kbase_t = kt * KB;
        #pragma unroll
        for (int fr = 0; fr < 4; ++fr) {
            if (kbase_t + fr * 16 <= qmax_w) {     // wave-uniform frag skip (causal)
                f32x4 a1 = {0.f, 0.f, 0.f, 0.f};
                f32x4 a2 = {0.f, 0.f, 0.f, 0.f};
                const int kr    = fr * 16 + c;     // A-frag row = k row in tile
                const int rbase = kr * 256;
                const int sw    = (kr & 7) << 4;
                #pragma unroll
                for (int d = 0; d < 4; ++d) {
                    int off = rbase + (((d * 64) + grp * 16) ^ sw);
                    half8 ah = *(const half8*)((const char*)khi  + off);
                    half8 am = *(const half8*)((const char*)kmid + off);
                    a1 = __builtin_amdgcn_mfma_f32_16x16x32_f16(ah, qhi[d],  a1, 0, 0, 0);
                    a2 = __builtin_amdgcn_mfma_f32_16x16x32_f16(ah, qmid[d], a2, 0, 0, 0);
                    a2 = __builtin_amdgcn_mfma_f32_16x16x32_f16(am, qhi[d],  a2, 0, 0, 0);
                }
                #pragma unroll
                for (int r = 0; r < 4; ++r) {
                    float s = fmaf(a2[r], INV2P11, a1[r]) * scale;
                    int kg = kbase_t + fr * 16 + grp * 4 + r;          // C row = k index
                    if (kg <= qrow) {
                        if (s > t[NC - 1]) {
                            float mo = t[0];
                            ins8p(t, ti, s, kg);
                            float mn = t[0];
                            if (mn != mo) Zr *= __expf(mo - mn);       // mo=-inf -> Zr*0=0, safe
                        }
                        Zr += __expf(s - t[0]);                        // t[0] finite here
                    }
                }
            }
        }
    }

    // ---- merge the 4 lanes holding each q-row (xor 16, 32) ----
    #pragma unroll
    for (int off = 16; off < 64; off <<= 1) {
        float zo = __shfl_xor(Zr, off, 64);
        float to[NC]; int io[NC];
        #pragma unroll
        for (int i = 0; i < NC; ++i) {
            to[i] = __shfl_xor(t[i], off, 64);
            io[i] = __shfl_xor(ti[i], off, 64);
        }
        float ms = t[0], mo = to[0];
        float mN = fmaxf(ms, mo);
        float fs = (ms == mN) ? 1.f : __expf(ms - mN);
        float fo = (mo == mN) ? 1.f : __expf(mo - mN);
        Zr = Zr * fs + zo * fo;
        #pragma unroll
        for (int i = 0; i < NC; ++i) ins8p(t, ti, to[i], io[i]);
    }

    // ---- borderline refinement: rank-5/6 margin < EPS -> recompute top-8 with the
    // round-0-replica sequential fp32 scorer (rounding-matched to the np reference) ----
    // (group-uniform branch: the 4 lanes of a row share identical t[])
    if (qrow >= Kv && (t[TOPK - 1] - t[TOPK]) < EPS_REF) {
        const float* qrp = Q + ((size_t)bh * SEQ + qrow) * DK;
        float rv0 = -INFINITY, rv1 = -INFINITY;
        int   ri0 = ti[grp * 2], ri1 = ti[grp * 2 + 1];
        if (t[grp * 2] != -INFINITY)
            rv0 = ref_score(qrp, Km + ((size_t)bh * SEQ + ri0) * DK, scale);
        if (t[grp * 2 + 1] != -INFINITY)
            rv1 = ref_score(qrp, Km + ((size_t)bh * SEQ + ri1) * DK, scale);
        // gather all 8 refined (value,index) to each lane of the 4-lane group
        float av[NC]; int ai[NC];
        #pragma unroll
        for (int j = 0; j < NC; ++j) {
            int src = (lane & 15) | ((j >> 1) << 4);
            av[j] = __shfl((j & 1) ? rv1 : rv0, src, 64);
            ai[j] = __shfl((j & 1) ? ri1 : ri0, src, 64);
        }
        // full bubble sort desc (static indexing)
        #pragma unroll
        for (int a = 1; a < NC; ++a) {
            #pragma unroll
            for (int b = NC - 1; b > 0; --b) {
                if (av[b] > av[b - 1]) {
                    float tv = av[b]; av[b] = av[b - 1]; av[b - 1] = tv;
                    int   tj = ai[b]; ai[b] = ai[b - 1]; ai[b - 1] = tj;
                }
            }
        }
        #pragma unroll
        for (int i = 0; i < NC; ++i) { t[i] = av[i]; ti[i] = ai[i]; }
    }

    // ---- per-row coefficients (lanes 0..15 of each wave) ----
    if (grp == 0) {
        const float m1 = t[0];
        const float invZ = 1.f / Zr;
        if (qrow >= Kv) {
            // kept set: p_i >= kth_p (ties included, matching `scores_b - kth >= 0`)
            float p[NC];
            #pragma unroll
            for (int i = 0; i < NC; ++i)
                p[i] = (t[i] == -INFINITY) ? -1.f : expf(t[i] - m1) * invZ;
            const float kth_p = p[TOPK - 1];       // 5th largest (valid: q>=5 -> >=6 entries)
            int n = 0; float wsum = 0.f;
            #pragma unroll
            for (int i = 0; i < NC; ++i) {
                if (t[i] != -INFINITY && p[i] >= kth_p) {
                    float wv = expf(p[i]);
                    s_coef[w][c][n] = wv;
                    s_idx [w][c][n] = ti[i];
                    wsum += wv;
                    ++n;
                }
            }
            float iw = 1.f / wsum;
            for (int i = 0; i < n; ++i) s_coef[w][c][i] *= iw;
            s_cnt[w][c] = n;
            s_ext[w][c] = 0.f;
        } else if (qrow == 0) {
            s_cnt[w][c] = 0;
            s_ext[w][c] = 0.f;
        } else {
            // rows 1..Kv-1: all q+1 scores present in t[0..q]; softmax2 over
            // [p_0..p_q, 0 x (1023-q)]: Z2 = sum exp(p_j) + (1023-q)
            float z2 = (float)(SEQ - 1 - qrow);
            float ex[TOPK];
            #pragma unroll
            for (int i = 0; i < TOPK; ++i) {
                if (i <= qrow) {
                    float p = expf(t[i] - m1) * invZ;
                    ex[i] = expf(p);
                    z2 += ex[i];
                } else ex[i] = 0.f;
            }
            float iz = 1.f / z2;
            #pragma unroll
            for (int i = 0; i < TOPK; ++i) {
                if (i <= qrow) {
                    s_coef[w][c][i] = (ex[i] - 1.f) * iz;
                    s_idx [w][c][i] = ti[i];
                }
            }
            s_cnt[w][c] = qrow + 1;
            s_ext[w][c] = iz;            // weight of SV (all-V column sum) term
        }
    }
    __syncthreads();                     // coef handoff

    // ---- gather: out[row] = sum_i coef_i * V[idx_i] (+ ext * SV) ----
    const float* vb = V + (size_t)bh * SEQ * DK;
    #pragma unroll 2
    for (int r = 0; r < 16; ++r) {
        const int row = qb + w * 16 + r;
        const int n = s_cnt[w][r];
        const float e = s_ext[w][r];
        float a0, a1v;
        if (e != 0.f) { a0 = e * s_sv[2 * lane]; a1v = e * s_sv[2 * lane + 1]; }
        else          { a0 = 0.f; a1v = 0.f; }
        for (int i = 0; i < n; ++i) {
            float cf = s_coef[w][r][i];
            int   ji = s_idx [w][r][i];
            const float2 v2 = *(const float2*)(vb + (size_t)ji * DK + 2 * lane);
            a0  = fmaf(cf, v2.x, a0);
            a1v = fmaf(cf, v2.y, a1v);
        }
        float2 o; o.x = a0; o.y = a1v;
        *(float2*)(out + ((size_t)bh * SEQ + row) * DK + 2 * lane) = o;
    }
}

extern "C" void kernel_launch(void* const* d_in, const int* in_sizes, int n_in,
                              void* d_out, int out_size, void* d_ws, size_t ws_size,
                              hipStream_t stream) {
    const float* q    = (const float*)d_in[0];
    const float* k    = (const float*)d_in[1];
    const float* v    = (const float*)d_in[2];
    // d_in[3] = tril mask, implied by kg <= qrow
    const int*   kidx = (const int*)d_in[4];
    float* out = (float*)d_out;

    dim3 grid(SEQ / QB, BSZ * NH);
    attn_topk_mfma<<<grid, NT, 0, stream>>>(q, k, v, kidx, out);
}